// Round 7
// baseline (679.806 us; speedup 1.0000x reference)
//
#include <hip/hip_runtime.h>

#define NB 8
#define NC 512
#define NPIX 4096
#define LOG2E 1.44269504088896340736f
#define C0TERM 28.853900817779268f   // 20*log2(e): p = exp2(s*log2e - C0TERM) = exp(s-20)

typedef __attribute__((ext_vector_type(4))) float f32x4;
typedef __attribute__((ext_vector_type(8))) short bf16x8;
typedef __attribute__((ext_vector_type(4))) unsigned short u16x4;

static __device__ __forceinline__ short f2bf(float f){
    union { float f; unsigned u; } v; v.f = f;
    unsigned r = v.u + 0x7fffu + ((v.u >> 16) & 1u);
    return (short)(r >> 16);
}

static __device__ __forceinline__ void gload16(const void* g, void* l){
    __builtin_amdgcn_global_load_lds(
        (const __attribute__((address_space(1))) char*)g,
        (__attribute__((address_space(3))) char*)l, 16, 0, 0);
}

// ---------------- weight f32 -> bf16 ----------------
__global__ void k_wconv(const float* __restrict__ wq, const float* __restrict__ wk,
                        const float* __restrict__ wv,
                        short* __restrict__ wqb, short* __restrict__ wkb,
                        short* __restrict__ wvb){
    int i = blockIdx.x * 256 + threadIdx.x;
    if (i < 64*NC){ wqb[i] = f2bf(wq[i]); wkb[i] = f2bf(wk[i]); }
    if (i < NC*NC){ wvb[i] = f2bf(wv[i]); }
}

// ---------------- Q projection (O=64) ----------------
__global__ __launch_bounds__(256) void k_projq(const float* __restrict__ X,
                                               const short* __restrict__ W,
                                               const float* __restrict__ bias,
                                               short* __restrict__ out){
    const int b = blockIdx.y;
    const int wv = threadIdx.x >> 6;
    const int lane = threadIdx.x & 63;
    const int g = lane >> 4, c16 = lane & 15;
    const int n0w = blockIdx.x * 64 + wv * 16;
    const float* Xb = X + (size_t)b * NC * NPIX;

    f32x4 acc[4];
#pragma unroll
    for (int f = 0; f < 4; ++f) acc[f] = (f32x4){0.f,0.f,0.f,0.f};

    for (int c0 = 0; c0 < NC; c0 += 32){
        bf16x8 a;
#pragma unroll
        for (int j = 0; j < 8; ++j)
            a[j] = f2bf(Xb[(size_t)(c0 + 8*g + j) * NPIX + n0w + c16]);
#pragma unroll
        for (int f = 0; f < 4; ++f){
            bf16x8 bfr = *(const bf16x8*)(W + (size_t)(f*16 + c16) * NC + c0 + 8*g);
            acc[f] = __builtin_amdgcn_mfma_f32_16x16x32_bf16(a, bfr, acc[f], 0, 0, 0);
        }
    }
#pragma unroll
    for (int f = 0; f < 4; ++f){
        int o = f*16 + c16;
        float bo = bias[o];
#pragma unroll
        for (int i = 0; i < 4; ++i)
            out[((size_t)b*NPIX + n0w + 4*g + i)*64 + o] = f2bf(acc[f][i] + bo);
    }
}

// ---------------- fused K+V projection (one pass over view2) ----------------
__global__ __launch_bounds__(256) void k_projkv(const float* __restrict__ X,
                                                const short* __restrict__ Wv_,
                                                const float* __restrict__ bv_,
                                                const short* __restrict__ Wk_,
                                                const float* __restrict__ bk_,
                                                short* __restrict__ vout,
                                                short* __restrict__ kout){
    const int b = blockIdx.y;
    const int wv = threadIdx.x >> 6;
    const int lane = threadIdx.x & 63;
    const int g = lane >> 4, c16 = lane & 15;
    const int n0w = blockIdx.x * 32 + (wv & 1) * 16;
    const int oh = wv >> 1;
    const int o0v = oh * 256;
    const int o0k = oh * 32;
    const float* Xb = X + (size_t)b * NC * NPIX;

    f32x4 accv[16], acck[2];
#pragma unroll
    for (int f = 0; f < 16; ++f) accv[f] = (f32x4){0.f,0.f,0.f,0.f};
#pragma unroll
    for (int f = 0; f < 2;  ++f) acck[f] = (f32x4){0.f,0.f,0.f,0.f};

    for (int c0 = 0; c0 < NC; c0 += 32){
        bf16x8 a;
#pragma unroll
        for (int j = 0; j < 8; ++j)
            a[j] = f2bf(Xb[(size_t)(c0 + 8*g + j) * NPIX + n0w + c16]);
#pragma unroll
        for (int f = 0; f < 16; ++f){
            bf16x8 bfr = *(const bf16x8*)(Wv_ + (size_t)(o0v + f*16 + c16) * NC + c0 + 8*g);
            accv[f] = __builtin_amdgcn_mfma_f32_16x16x32_bf16(a, bfr, accv[f], 0, 0, 0);
        }
#pragma unroll
        for (int f = 0; f < 2; ++f){
            bf16x8 bfr = *(const bf16x8*)(Wk_ + (size_t)(o0k + f*16 + c16) * NC + c0 + 8*g);
            acck[f] = __builtin_amdgcn_mfma_f32_16x16x32_bf16(a, bfr, acck[f], 0, 0, 0);
        }
    }
#pragma unroll
    for (int f = 0; f < 16; ++f){
        int o = o0v + f*16 + c16;
        float bo = bv_[o];
        u16x4 pk;
#pragma unroll
        for (int i = 0; i < 4; ++i) pk[i] = (unsigned short)f2bf(accv[f][i] + bo);
        *(u16x4*)(vout + ((size_t)b*NC + o)*NPIX + n0w + 4*g) = pk;
    }
#pragma unroll
    for (int f = 0; f < 2; ++f){
        int o = o0k + f*16 + c16;
        float bo = bk_[o];
#pragma unroll
        for (int i = 0; i < 4; ++i)
            kout[((size_t)b*NPIX + n0w + 4*g + i)*64 + o] = f2bf(acck[f][i] + bo);
    }
}

// ---------------- pass 1: P = exp(QK^T - 20) bf16 (coalesced via LDS), L partials ----
// block 256 thr / 4 waves; tile m 64 x n 256; wave wv owns n-sub [wv*64,+64).
// swapped mfma(K,Q): lane holds m=c16, n=4g+i -> packed 8B ds_write (XOR-swizzled),
// then block-coalesced 512B-row stores to global P.
__global__ __launch_bounds__(256) void k_qk(const short* __restrict__ qb,
                                            const short* __restrict__ kb,
                                            short* __restrict__ P,
                                            float* __restrict__ Lpart,
                                            int b0){
    __shared__ __align__(16) short Pt[64*256];     // 32 KB, row stride 512B
    const int m0 = blockIdx.x * 64;
    const int n0 = blockIdx.y * 256;
    const int bz = blockIdx.z;            // local (chunk) batch
    const int b  = b0 + bz;               // global batch
    const int wv = threadIdx.x >> 6;
    const int lane = threadIdx.x & 63;
    const int g = lane >> 4, c16 = lane & 15;
    const int nsub = wv * 64;

    bf16x8 qf[4][2];
#pragma unroll
    for (int mf = 0; mf < 4; ++mf)
#pragma unroll
        for (int kk = 0; kk < 2; ++kk)
            qf[mf][kk] = *(const bf16x8*)(qb + ((size_t)b*NPIX + m0 + mf*16 + c16)*64 + kk*32 + 8*g);

    float lsum[4] = {0.f,0.f,0.f,0.f};
    char* Ptb = (char*)Pt;

#pragma unroll
    for (int nf = 0; nf < 4; ++nf){
        bf16x8 kf0 = *(const bf16x8*)(kb + ((size_t)b*NPIX + n0 + nsub + nf*16 + c16)*64 + 8*g);
        bf16x8 kf1 = *(const bf16x8*)(kb + ((size_t)b*NPIX + n0 + nsub + nf*16 + c16)*64 + 32 + 8*g);
#pragma unroll
        for (int mf = 0; mf < 4; ++mf){
            f32x4 s = (f32x4){0.f,0.f,0.f,0.f};
            s = __builtin_amdgcn_mfma_f32_16x16x32_bf16(kf0, qf[mf][0], s, 0,0,0);
            s = __builtin_amdgcn_mfma_f32_16x16x32_bf16(kf1, qf[mf][1], s, 0,0,0);
            u16x4 pk;
#pragma unroll
            for (int i = 0; i < 4; ++i){
                float p = exp2f(fmaf(s[i], LOG2E, -C0TERM));
                lsum[mf] += p;
                pk[i] = (unsigned short)f2bf(p);
            }
            int m = mf*16 + c16;
            int ncol = nsub + nf*16 + 4*g;
            *(u16x4*)(Ptb + m*512 + ((2*ncol) ^ ((m&7)<<4))) = pk;
        }
    }
    __syncthreads();

    // coalesced global store: 8 passes, each 256 thr cover 8 rows x 512B
    {
        char* Pgb = (char*)(P + ((size_t)bz*NPIX + m0)*NPIX + n0);
        const int chunk = threadIdx.x & 31;
        const int row8  = threadIdx.x >> 5;
#pragma unroll
        for (int p = 0; p < 8; ++p){
            int row = p*8 + row8;
            f32x4 v = *(const f32x4*)(Ptb + row*512 + ((chunk*16) ^ ((row&7)<<4)));
            *(f32x4*)(Pgb + (size_t)row*(NPIX*2) + chunk*16) = v;
        }
    }

    // L partials: reduce over g-groups; lane<16 holds m=c16 sum over this wave's 64 n
#pragma unroll
    for (int mf = 0; mf < 4; ++mf){
        lsum[mf] += __shfl_xor(lsum[mf], 16);
        lsum[mf] += __shfl_xor(lsum[mf], 32);
    }
    if (lane < 16){
        size_t base = ((size_t)bz*64 + blockIdx.y*4 + wv)*NPIX + m0 + lane;
#pragma unroll
        for (int mf = 0; mf < 4; ++mf)
            Lpart[base + mf*16] = lsum[mf];
    }
}

// ---------------- L reduce: scale[bz][m] = gamma / sum ----------------
__global__ __launch_bounds__(256) void k_lred(const float* __restrict__ Lpart,
                                              const float* __restrict__ gamma,
                                              float* __restrict__ scale){
    int idx = blockIdx.x * 256 + threadIdx.x;       // nb*4096 entries
    int bz = idx >> 12, m = idx & 4095;
    float s = 0.f;
    for (int sl = 0; sl < 64; ++sl)
        s += Lpart[((size_t)bz*64 + sl)*NPIX + m];
    scale[idx] = gamma[0] / s;
}

// ---------------- pass 2: PV GEMM (m97 structure) + epilogue ----------------
// out[c][m] = scale[m]*(sum_n V[c][n]*P[m][n]) + view1[c][m]
// tile 128c x 128m x 64n; 256 thr / 4 waves; global_load_lds width-16 staging,
// double-buffered LDS, one barrier per K-step (m97: 874 TF-class).
__global__ __launch_bounds__(256) void k_pv(const short* __restrict__ vb,
                                            const short* __restrict__ P,
                                            const float* __restrict__ scale,
                                            const float* __restrict__ view1,
                                            float* __restrict__ out,
                                            int b0){
    __shared__ __align__(16) short At[2][128*64];   // V rows (c), 32 KB
    __shared__ __align__(16) short Bt[2][128*64];   // P rows (m), 32 KB
    const int c0 = blockIdx.x * 128;
    const int m0 = blockIdx.y * 128;
    const int bz = blockIdx.z;
    const int b  = b0 + bz;
    const int wv = threadIdx.x >> 6;
    const int lane = threadIdx.x & 63;
    const int g = lane >> 4, c16 = lane & 15;
    const int wc = wv & 1, wm = wv >> 1;
    const int lrow = lane >> 3;
    const int lcol = (lane & 7) * 16;

    const char* Vg = (const char*)(vb + ((size_t)b*NC + c0)*NPIX);
    const char* Pg = (const char*)(P + ((size_t)bz*NPIX + m0)*NPIX);

    f32x4 acc[4][4];
#pragma unroll
    for (int cf = 0; cf < 4; ++cf)
#pragma unroll
        for (int mf = 0; mf < 4; ++mf) acc[cf][mf] = (f32x4){0.f,0.f,0.f,0.f};

    auto stage = [&](int buf, int t){
        size_t nbyte = (size_t)t * 64 * 2;
#pragma unroll
        for (int j = 0; j < 4; ++j){
            int r0 = wv*32 + j*8;
            int row = r0 + lrow;
            gload16(Vg + (size_t)row*(NPIX*2) + nbyte + lcol, (char*)&At[buf][0] + r0*128);
            gload16(Pg + (size_t)row*(NPIX*2) + nbyte + lcol, (char*)&Bt[buf][0] + r0*128);
        }
    };

    stage(0, 0);
    __syncthreads();

    for (int t = 0; t < 64; ++t){
        int buf = t & 1;
        if (t < 63) stage(buf ^ 1, t + 1);
        const char* A  = (const char*)&At[buf][0];
        const char* Bp = (const char*)&Bt[buf][0];
#pragma unroll
        for (int kk = 0; kk < 2; ++kk){
            bf16x8 af[4], bfm[4];
#pragma unroll
            for (int f = 0; f < 4; ++f){
                af[f]  = *(const bf16x8*)(A  + (wc*64 + f*16 + c16)*128 + kk*64 + g*16);
                bfm[f] = *(const bf16x8*)(Bp + (wm*64 + f*16 + c16)*128 + kk*64 + g*16);
            }
#pragma unroll
            for (int cf = 0; cf < 4; ++cf)
#pragma unroll
                for (int mf = 0; mf < 4; ++mf)
                    acc[cf][mf] = __builtin_amdgcn_mfma_f32_16x16x32_bf16(af[cf], bfm[mf], acc[cf][mf], 0,0,0);
        }
        __syncthreads();
    }

    // epilogue: D row = c (A-row), D col = m (B-row)
    float sc[4];
#pragma unroll
    for (int mf = 0; mf < 4; ++mf)
        sc[mf] = scale[(size_t)bz*NPIX + m0 + wm*64 + mf*16 + c16];
#pragma unroll
    for (int cf = 0; cf < 4; ++cf){
#pragma unroll
        for (int mf = 0; mf < 4; ++mf){
            int m = m0 + wm*64 + mf*16 + c16;
#pragma unroll
            for (int i = 0; i < 4; ++i){
                int c = c0 + wc*64 + cf*16 + 4*g + i;
                size_t idx = ((size_t)b*NC + c)*NPIX + m;
                out[idx] = sc[mf]*acc[cf][mf][i] + view1[idx];
            }
        }
    }
}

// ================= fallback fused attention (R4, 390us) — used if ws too small =========
__global__ __launch_bounds__(512, 2) void k_attn(const short* __restrict__ qb,
                                                 const short* __restrict__ kb,
                                                 const short* __restrict__ vb,
                                                 const float* __restrict__ view1,
                                                 const float* __restrict__ gamma,
                                                 float* __restrict__ out){
    __shared__ __align__(16) short P[2][64*64];
    __shared__ float Lred[128];

    const int bid = blockIdx.x;
    const int b  = bid & 7;
    const int m0 = (bid >> 3) * 64;
    const int wv = threadIdx.x >> 6;
    const int lane = threadIdx.x & 63;
    const int g = lane >> 4, c16 = lane & 15;
    const int msubA = (wv & 3) * 16;
    const int nhalf = wv >> 2;
    const int c0w = wv * 64;

    const short* qrow = qb + ((size_t)b*NPIX + m0 + msubA + c16)*64 + 8*g;
    bf16x8 qa0 = *(const bf16x8*)qrow;
    bf16x8 qa1 = *(const bf16x8*)(qrow + 32);

    const size_t kbase = (size_t)b * NPIX * 64;
    const int mrow = msubA + c16;
    const int swz = (mrow & 7) << 4;
    float Lacc = 0.f;

    f32x4 acc[4][4];
#pragma unroll
    for (int f = 0; f < 4; ++f)
#pragma unroll
        for (int cf = 0; cf < 4; ++cf) acc[f][cf] = (f32x4){0.f,0.f,0.f,0.f};

    char* Pb0 = (char*)&P[0][0];
    char* Pb1 = (char*)&P[1][0];

    bf16x8 vrA[8], vrB[8], krA[4], krB[4];

    auto loadK = [&](int t, bf16x8 (&kr)[4]){
        const short* kp = kb + kbase + (size_t)(t*64 + nhalf*32 + c16)*64 + 8*g;
        kr[0] = *(const bf16x8*)kp;
        kr[1] = *(const bf16x8*)(kp + 32);
        kr[2] = *(const bf16x8*)(kp + 16*64);
        kr[3] = *(const bf16x8*)(kp + 16*64 + 32);
    };
    auto loadV = [&](int t, bf16x8 (&vr)[8]){
#pragma unroll
        for (int h = 0; h < 2; ++h)
#pragma unroll
            for (int cf = 0; cf < 4; ++cf)
                vr[h*4+cf] = *(const bf16x8*)(vb + ((size_t)b*NC + c0w + cf*16 + c16)*NPIX
                                              + t*64 + h*32 + 8*g);
    };

    auto compA = [&](bf16x8 kA, bf16x8 kB, int fn, char* pb){
        f32x4 s = (f32x4){0.f,0.f,0.f,0.f};
        s = __builtin_amdgcn_mfma_f32_16x16x32_bf16(kA, qa0, s, 0,0,0);
        s = __builtin_amdgcn_mfma_f32_16x16x32_bf16(kB, qa1, s, 0,0,0);
        u16x4 pk;
#pragma unroll
        for (int i = 0; i < 4; ++i){
            float p = exp2f(fmaf(s[i], LOG2E, -C0TERM));
            Lacc += p;
            pk[i] = (unsigned short)f2bf(p);
        }
        int nrel0 = nhalf*32 + fn*16 + 4*g;
        *(u16x4*)(pb + mrow*128 + ((2*nrel0) ^ swz)) = pk;
    };

    auto phaseB = [&](const char* pc, const bf16x8 (&vr)[8]){
#pragma unroll
        for (int h = 0; h < 2; ++h){
            bf16x8 pa[4];
#pragma unroll
            for (int f = 0; f < 4; ++f){
                int row = f*16 + c16;
                pa[f] = *(const bf16x8*)(pc + row*128 + ((h*64 + g*16) ^ ((row&7)<<4)));
            }
#pragma unroll
            for (int cf = 0; cf < 4; ++cf)
#pragma unroll
                for (int f = 0; f < 4; ++f)
                    acc[f][cf] = __builtin_amdgcn_mfma_f32_16x16x32_bf16(pa[f], vr[h*4+cf], acc[f][cf], 0,0,0);
        }
    };

    auto iter = [&](int t, char* bufA, const char* bufB,
                    const bf16x8 (&vcur)[8], bf16x8 (&vnext)[8],
                    const bf16x8 (&kcur)[4], bf16x8 (&knext)[4]){
        loadV(t+1, vnext);
        loadK(t+2 < 64 ? t+2 : 63, knext);
        __builtin_amdgcn_s_setprio(1);
        phaseB(bufB, vcur);
        __builtin_amdgcn_s_setprio(0);
        compA(kcur[0], kcur[1], 0, bufA);
        compA(kcur[2], kcur[3], 1, bufA);
        asm volatile("s_waitcnt lgkmcnt(0)" ::: "memory");
        __builtin_amdgcn_s_barrier();
    };

    loadV(0, vrA);
    loadK(0, krA);
    loadK(1, krB);
    compA(krA[0], krA[1], 0, Pb0);
    compA(krA[2], krA[3], 1, Pb0);
    asm volatile("s_waitcnt lgkmcnt(0)" ::: "memory");
    __builtin_amdgcn_s_barrier();

    for (int t2 = 0; t2 < 31; ++t2){
        iter(2*t2,     Pb1, Pb0, vrA, vrB, krB, krA);
        iter(2*t2 + 1, Pb0, Pb1, vrB, vrA, krA, krB);
    }
    iter(62, Pb1, Pb0, vrA, vrB, krB, krA);
    __builtin_amdgcn_s_setprio(1);
    phaseB(Pb1, vrB);
    __builtin_amdgcn_s_setprio(0);

    Lacc += __shfl_xor(Lacc, 16);
    Lacc += __shfl_xor(Lacc, 32);
    if (lane < 16) Lred[nhalf*64 + msubA + lane] = Lacc;
    __syncthreads();

    float gm = gamma[0];
#pragma unroll
    for (int f = 0; f < 4; ++f){
        float sc[4];
#pragma unroll
        for (int i = 0; i < 4; ++i){
            int r = f*16 + 4*g + i;
            float Ls = Lred[r] + Lred[64 + r];
            sc[i] = gm / Ls;
        }
#pragma unroll
        for (int cf = 0; cf < 4; ++cf){
            int c = c0w + cf*16 + c16;
            size_t base = ((size_t)b*NC + c)*NPIX + m0 + f*16 + 4*g;
            f32x4 v1 = *(const f32x4*)(view1 + base);
            f32x4 r;
#pragma unroll
            for (int i = 0; i < 4; ++i) r[i] = sc[i]*acc[f][cf][i] + v1[i];
            *(f32x4*)(out + base) = r;
        }
    }
}

extern "C" void kernel_launch(void* const* d_in, const int* in_sizes, int n_in,
                              void* d_out, int out_size, void* d_ws, size_t ws_size,
                              hipStream_t stream){
    const float* view1 = (const float*)d_in[0];
    const float* view2 = (const float*)d_in[1];
    const float* Wq    = (const float*)d_in[2];
    const float* bq    = (const float*)d_in[3];
    const float* Wk    = (const float*)d_in[4];
    const float* bk    = (const float*)d_in[5];
    const float* Wv    = (const float*)d_in[6];
    const float* bv    = (const float*)d_in[7];
    const float* gamma = (const float*)d_in[8];
    float* out = (float*)d_out;

    char* ws = (char*)d_ws;
    short* qbuf = (short*)(ws);                                   // 4 MB  (B,N,64) bf16
    short* kbuf = (short*)(ws + (size_t)4*1024*1024);             // 4 MB  (B,N,64) bf16
    short* vbuf = (short*)(ws + (size_t)8*1024*1024);             // 32 MB (B,C,N) bf16
    short* wqb  = (short*)(ws + (size_t)40*1024*1024);            // 64 KB
    short* wkb  = (short*)(ws + (size_t)40*1024*1024 + 64*1024);  // 64 KB
    short* wvb  = (short*)(ws + (size_t)40*1024*1024 + 128*1024); // 512 KB
    float* scl  = (float*)(ws + (size_t)41*1024*1024);            // 128 KB (chunk-local)
    float* Lpart= (float*)(ws + (size_t)42*1024*1024);            // 8 MB max (chunk-local)
    short* Pbuf = (short*)(ws + (size_t)50*1024*1024);            // 32 MB * nbc

    const size_t FIXED = (size_t)50*1024*1024;
    const size_t PPB   = (size_t)NPIX*NPIX*2;   // 32 MB per batch
    int nbc = 0;
    if (ws_size > FIXED){
        size_t nn = (ws_size - FIXED) / PPB;
        nbc = nn > 8 ? 8 : (int)nn;
    }

    hipLaunchKernelGGL(k_wconv, dim3(1024), dim3(256), 0, stream, Wq, Wk, Wv, wqb, wkb, wvb);
    hipLaunchKernelGGL(k_projq,  dim3(64, 8),  dim3(256), 0, stream, view1, wqb, bq, qbuf);
    hipLaunchKernelGGL(k_projkv, dim3(128, 8), dim3(256), 0, stream, view2, wvb, bv, wkb, bk, vbuf, kbuf);

    if (nbc >= 1){
        for (int b0 = 0; b0 < NB; b0 += nbc){
            int nb = (NB - b0 < nbc) ? (NB - b0) : nbc;
            hipLaunchKernelGGL(k_qk,   dim3(64, 16, nb), dim3(256), 0, stream, qbuf, kbuf, Pbuf, Lpart, b0);
            hipLaunchKernelGGL(k_lred, dim3(nb*16),      dim3(256), 0, stream, Lpart, gamma, scl);
            hipLaunchKernelGGL(k_pv,   dim3(4, 32, nb),  dim3(256), 0, stream, vbuf, Pbuf, scl, view1, out, b0);
        }
    } else {
        hipLaunchKernelGGL(k_attn, dim3(512), dim3(512), 0, stream, qbuf, kbuf, vbuf, view1, gamma, out);
    }
}

// Round 8
// 458.351 us; speedup vs baseline: 1.4832x; 1.4832x over previous
//
#include <hip/hip_runtime.h>

#define NB 8
#define NC 512
#define NPIX 4096
#define LOG2E 1.44269504088896340736f
#define C0TERM 28.853900817779268f   // 20*log2(e): p = exp2(s*log2e - C0TERM) = exp(s-20)

typedef __attribute__((ext_vector_type(4))) float f32x4;
typedef __attribute__((ext_vector_type(8))) short bf16x8;
typedef __attribute__((ext_vector_type(4))) unsigned short u16x4;

static __device__ __forceinline__ short f2bf(float f){
    union { float f; unsigned u; } v; v.f = f;
    unsigned r = v.u + 0x7fffu + ((v.u >> 16) & 1u);
    return (short)(r >> 16);
}

static __device__ __forceinline__ void gload16(const void* g, void* l){
    __builtin_amdgcn_global_load_lds(
        (const __attribute__((address_space(1))) char*)g,
        (__attribute__((address_space(3))) char*)l, 16, 0, 0);
}

// ---------------- weight f32 -> bf16 ----------------
__global__ void k_wconv(const float* __restrict__ wq, const float* __restrict__ wk,
                        const float* __restrict__ wv,
                        short* __restrict__ wqb, short* __restrict__ wkb,
                        short* __restrict__ wvb){
    int i = blockIdx.x * 256 + threadIdx.x;
    if (i < 64*NC){ wqb[i] = f2bf(wq[i]); wkb[i] = f2bf(wk[i]); }
    if (i < NC*NC){ wvb[i] = f2bf(wv[i]); }
}

// ---------------- Q projection (O=64) ----------------
__global__ __launch_bounds__(256) void k_projq(const float* __restrict__ X,
                                               const short* __restrict__ W,
                                               const float* __restrict__ bias,
                                               short* __restrict__ out){
    const int b = blockIdx.y;
    const int wv = threadIdx.x >> 6;
    const int lane = threadIdx.x & 63;
    const int g = lane >> 4, c16 = lane & 15;
    const int n0w = blockIdx.x * 64 + wv * 16;
    const float* Xb = X + (size_t)b * NC * NPIX;

    f32x4 acc[4];
#pragma unroll
    for (int f = 0; f < 4; ++f) acc[f] = (f32x4){0.f,0.f,0.f,0.f};

    for (int c0 = 0; c0 < NC; c0 += 32){
        bf16x8 a;
#pragma unroll
        for (int j = 0; j < 8; ++j)
            a[j] = f2bf(Xb[(size_t)(c0 + 8*g + j) * NPIX + n0w + c16]);
#pragma unroll
        for (int f = 0; f < 4; ++f){
            bf16x8 bfr = *(const bf16x8*)(W + (size_t)(f*16 + c16) * NC + c0 + 8*g);
            acc[f] = __builtin_amdgcn_mfma_f32_16x16x32_bf16(a, bfr, acc[f], 0, 0, 0);
        }
    }
#pragma unroll
    for (int f = 0; f < 4; ++f){
        int o = f*16 + c16;
        float bo = bias[o];
#pragma unroll
        for (int i = 0; i < 4; ++i)
            out[((size_t)b*NPIX + n0w + 4*g + i)*64 + o] = f2bf(acc[f][i] + bo);
    }
}

// ---------------- fused K+V projection (one pass over view2) ----------------
__global__ __launch_bounds__(256) void k_projkv(const float* __restrict__ X,
                                                const short* __restrict__ Wv_,
                                                const float* __restrict__ bv_,
                                                const short* __restrict__ Wk_,
                                                const float* __restrict__ bk_,
                                                short* __restrict__ vout,
                                                short* __restrict__ kout){
    const int b = blockIdx.y;
    const int wv = threadIdx.x >> 6;
    const int lane = threadIdx.x & 63;
    const int g = lane >> 4, c16 = lane & 15;
    const int n0w = blockIdx.x * 32 + (wv & 1) * 16;
    const int oh = wv >> 1;
    const int o0v = oh * 256;
    const int o0k = oh * 32;
    const float* Xb = X + (size_t)b * NC * NPIX;

    f32x4 accv[16], acck[2];
#pragma unroll
    for (int f = 0; f < 16; ++f) accv[f] = (f32x4){0.f,0.f,0.f,0.f};
#pragma unroll
    for (int f = 0; f < 2;  ++f) acck[f] = (f32x4){0.f,0.f,0.f,0.f};

    for (int c0 = 0; c0 < NC; c0 += 32){
        bf16x8 a;
#pragma unroll
        for (int j = 0; j < 8; ++j)
            a[j] = f2bf(Xb[(size_t)(c0 + 8*g + j) * NPIX + n0w + c16]);
#pragma unroll
        for (int f = 0; f < 16; ++f){
            bf16x8 bfr = *(const bf16x8*)(Wv_ + (size_t)(o0v + f*16 + c16) * NC + c0 + 8*g);
            accv[f] = __builtin_amdgcn_mfma_f32_16x16x32_bf16(a, bfr, accv[f], 0, 0, 0);
        }
#pragma unroll
        for (int f = 0; f < 2; ++f){
            bf16x8 bfr = *(const bf16x8*)(Wk_ + (size_t)(o0k + f*16 + c16) * NC + c0 + 8*g);
            acck[f] = __builtin_amdgcn_mfma_f32_16x16x32_bf16(a, bfr, acck[f], 0, 0, 0);
        }
    }
#pragma unroll
    for (int f = 0; f < 16; ++f){
        int o = o0v + f*16 + c16;
        float bo = bv_[o];
        u16x4 pk;
#pragma unroll
        for (int i = 0; i < 4; ++i) pk[i] = (unsigned short)f2bf(accv[f][i] + bo);
        *(u16x4*)(vout + ((size_t)b*NC + o)*NPIX + n0w + 4*g) = pk;
    }
#pragma unroll
    for (int f = 0; f < 2; ++f){
        int o = o0k + f*16 + c16;
        float bo = bk_[o];
#pragma unroll
        for (int i = 0; i < 4; ++i)
            kout[((size_t)b*NPIX + n0w + 4*g + i)*64 + o] = f2bf(acck[f][i] + bo);
    }
}

// ---------------- pass 1: P = exp(QK^T - 20) bf16 (coalesced via LDS), L partials ----
__global__ __launch_bounds__(256) void k_qk(const short* __restrict__ qb,
                                            const short* __restrict__ kb,
                                            short* __restrict__ P,
                                            float* __restrict__ Lpart,
                                            int b0){
    __shared__ __align__(16) short Pt[64*256];     // 32 KB, row stride 512B
    const int m0 = blockIdx.x * 64;
    const int n0 = blockIdx.y * 256;
    const int bz = blockIdx.z;            // local (chunk) batch
    const int b  = b0 + bz;               // global batch
    const int wv = threadIdx.x >> 6;
    const int lane = threadIdx.x & 63;
    const int g = lane >> 4, c16 = lane & 15;
    const int nsub = wv * 64;

    bf16x8 qf[4][2];
#pragma unroll
    for (int mf = 0; mf < 4; ++mf)
#pragma unroll
        for (int kk = 0; kk < 2; ++kk)
            qf[mf][kk] = *(const bf16x8*)(qb + ((size_t)b*NPIX + m0 + mf*16 + c16)*64 + kk*32 + 8*g);

    float lsum[4] = {0.f,0.f,0.f,0.f};
    char* Ptb = (char*)Pt;

#pragma unroll
    for (int nf = 0; nf < 4; ++nf){
        bf16x8 kf0 = *(const bf16x8*)(kb + ((size_t)b*NPIX + n0 + nsub + nf*16 + c16)*64 + 8*g);
        bf16x8 kf1 = *(const bf16x8*)(kb + ((size_t)b*NPIX + n0 + nsub + nf*16 + c16)*64 + 32 + 8*g);
#pragma unroll
        for (int mf = 0; mf < 4; ++mf){
            f32x4 s = (f32x4){0.f,0.f,0.f,0.f};
            s = __builtin_amdgcn_mfma_f32_16x16x32_bf16(kf0, qf[mf][0], s, 0,0,0);
            s = __builtin_amdgcn_mfma_f32_16x16x32_bf16(kf1, qf[mf][1], s, 0,0,0);
            u16x4 pk;
#pragma unroll
            for (int i = 0; i < 4; ++i){
                float p = exp2f(fmaf(s[i], LOG2E, -C0TERM));
                lsum[mf] += p;
                pk[i] = (unsigned short)f2bf(p);
            }
            int m = mf*16 + c16;
            int ncol = nsub + nf*16 + 4*g;
            *(u16x4*)(Ptb + m*512 + ((2*ncol) ^ ((m&7)<<4))) = pk;
        }
    }
    __syncthreads();

    // coalesced global store: 8 passes, each 256 thr cover 8 rows x 512B
    {
        char* Pgb = (char*)(P + ((size_t)bz*NPIX + m0)*NPIX + n0);
        const int chunk = threadIdx.x & 31;
        const int row8  = threadIdx.x >> 5;
#pragma unroll
        for (int p = 0; p < 8; ++p){
            int row = p*8 + row8;
            f32x4 v = *(const f32x4*)(Ptb + row*512 + ((chunk*16) ^ ((row&7)<<4)));
            *(f32x4*)(Pgb + (size_t)row*(NPIX*2) + chunk*16) = v;
        }
    }

    // L partials
#pragma unroll
    for (int mf = 0; mf < 4; ++mf){
        lsum[mf] += __shfl_xor(lsum[mf], 16);
        lsum[mf] += __shfl_xor(lsum[mf], 32);
    }
    if (lane < 16){
        size_t base = ((size_t)bz*64 + blockIdx.y*4 + wv)*NPIX + m0 + lane;
#pragma unroll
        for (int mf = 0; mf < 4; ++mf)
            Lpart[base + mf*16] = lsum[mf];
    }
}

// ---------------- L reduce: scale[bz][m] = gamma / sum ----------------
__global__ __launch_bounds__(256) void k_lred(const float* __restrict__ Lpart,
                                              const float* __restrict__ gamma,
                                              float* __restrict__ scale){
    int idx = blockIdx.x * 256 + threadIdx.x;
    int bz = idx >> 12, m = idx & 4095;
    float s = 0.f;
    for (int sl = 0; sl < 64; ++sl)
        s += Lpart[((size_t)bz*64 + sl)*NPIX + m];
    scale[idx] = gamma[0] / s;
}

// ---------------- pass 2: PV GEMM (m97 structure + T2 swizzle) + epilogue ----------------
// out[c][m] = scale[m]*(sum_n V[c][n]*P[m][n]) + view1[c][m]
// tile 128c x 128m x 64n; 256 thr / 4 waves; global_load_lds width-16 staging with
// PRE-SWIZZLED global source (rule #21: linear LDS dest + inverse-swz source + swz read).
// Read XOR swz=(c16&7)<<4 breaks the 16-way stride-128B bank conflict (R7: 37.7M cycles).
// Block remap: p%8 == mtile%8 so the 4 c-blocks sharing a P-tile land on one XCD's L2.
__global__ __launch_bounds__(256) void k_pv(const short* __restrict__ vb,
                                            const short* __restrict__ P,
                                            const float* __restrict__ scale,
                                            const float* __restrict__ view1,
                                            float* __restrict__ out,
                                            int b0){
    __shared__ __align__(16) short At[2][128*64];   // V rows (c), 32 KB
    __shared__ __align__(16) short Bt[2][128*64];   // P rows (m), 32 KB
    const int p  = blockIdx.x + 4*blockIdx.y;       // 0..127
    const int mt = (p & 7) | (((p >> 5) & 3) << 3); // m-tile 0..31
    const int ct = (p >> 3) & 3;                    // c-tile 0..3
    const int c0 = ct * 128;
    const int m0 = mt * 128;
    const int bz = blockIdx.z;
    const int b  = b0 + bz;
    const int wv = threadIdx.x >> 6;
    const int lane = threadIdx.x & 63;
    const int g = lane >> 4, c16 = lane & 15;
    const int wc = wv & 1, wm = wv >> 1;
    const int lrow = lane >> 3;                     // 0..7
    const int srcg = (lane & 7) ^ lrow;             // pre-swizzled source granule
    const int swz  = (c16 & 7) << 4;                // read-side XOR

    const char* Vg = (const char*)(vb + ((size_t)b*NC + c0)*NPIX);
    const char* Pg = (const char*)(P + ((size_t)bz*NPIX + m0)*NPIX);

    f32x4 acc[4][4];
#pragma unroll
    for (int cf = 0; cf < 4; ++cf)
#pragma unroll
        for (int mf = 0; mf < 4; ++mf) acc[cf][mf] = (f32x4){0.f,0.f,0.f,0.f};

    auto stage = [&](int buf, int t){
        size_t nbyte = (size_t)t * 64 * 2;
#pragma unroll
        for (int j = 0; j < 4; ++j){
            int r0 = wv*32 + j*8;                   // r0&7 == 0 -> row&7 == lrow
            int row = r0 + lrow;
            gload16(Vg + (size_t)row*(NPIX*2) + nbyte + srcg*16, (char*)&At[buf][0] + r0*128);
            gload16(Pg + (size_t)row*(NPIX*2) + nbyte + srcg*16, (char*)&Bt[buf][0] + r0*128);
        }
    };

    stage(0, 0);
    __syncthreads();

    for (int t = 0; t < 64; ++t){
        int buf = t & 1;
        if (t < 63) stage(buf ^ 1, t + 1);
        const char* A  = (const char*)&At[buf][0];
        const char* Bp = (const char*)&Bt[buf][0];
#pragma unroll
        for (int kk = 0; kk < 2; ++kk){
            bf16x8 af[4], bfm[4];
#pragma unroll
            for (int f = 0; f < 4; ++f){
                af[f]  = *(const bf16x8*)(A  + (wc*64 + f*16 + c16)*128 + ((kk*64 + g*16) ^ swz));
                bfm[f] = *(const bf16x8*)(Bp + (wm*64 + f*16 + c16)*128 + ((kk*64 + g*16) ^ swz));
            }
#pragma unroll
            for (int cf = 0; cf < 4; ++cf)
#pragma unroll
                for (int mf = 0; mf < 4; ++mf)
                    acc[cf][mf] = __builtin_amdgcn_mfma_f32_16x16x32_bf16(af[cf], bfm[mf], acc[cf][mf], 0,0,0);
        }
        __syncthreads();
    }

    // epilogue: D row = c (A-row), D col = m (B-row)
    float sc[4];
#pragma unroll
    for (int mf = 0; mf < 4; ++mf)
        sc[mf] = scale[(size_t)bz*NPIX + m0 + wm*64 + mf*16 + c16];
#pragma unroll
    for (int cf = 0; cf < 4; ++cf){
#pragma unroll
        for (int mf = 0; mf < 4; ++mf){
            int m = m0 + wm*64 + mf*16 + c16;
#pragma unroll
            for (int i = 0; i < 4; ++i){
                int c = c0 + wc*64 + cf*16 + 4*g + i;
                size_t idx = ((size_t)b*NC + c)*NPIX + m;
                out[idx] = sc[mf]*acc[cf][mf][i] + view1[idx];
            }
        }
    }
}

// ================= fallback fused attention (R4, 390us) — used if ws too small =========
__global__ __launch_bounds__(512, 2) void k_attn(const short* __restrict__ qb,
                                                 const short* __restrict__ kb,
                                                 const short* __restrict__ vb,
                                                 const float* __restrict__ view1,
                                                 const float* __restrict__ gamma,
                                                 float* __restrict__ out){
    __shared__ __align__(16) short P[2][64*64];
    __shared__ float Lred[128];

    const int bid = blockIdx.x;
    const int b  = bid & 7;
    const int m0 = (bid >> 3) * 64;
    const int wv = threadIdx.x >> 6;
    const int lane = threadIdx.x & 63;
    const int g = lane >> 4, c16 = lane & 15;
    const int msubA = (wv & 3) * 16;
    const int nhalf = wv >> 2;
    const int c0w = wv * 64;

    const short* qrow = qb + ((size_t)b*NPIX + m0 + msubA + c16)*64 + 8*g;
    bf16x8 qa0 = *(const bf16x8*)qrow;
    bf16x8 qa1 = *(const bf16x8*)(qrow + 32);

    const size_t kbase = (size_t)b * NPIX * 64;
    const int mrow = msubA + c16;
    const int swz = (mrow & 7) << 4;
    float Lacc = 0.f;

    f32x4 acc[4][4];
#pragma unroll
    for (int f = 0; f < 4; ++f)
#pragma unroll
        for (int cf = 0; cf < 4; ++cf) acc[f][cf] = (f32x4){0.f,0.f,0.f,0.f};

    char* Pb0 = (char*)&P[0][0];
    char* Pb1 = (char*)&P[1][0];

    bf16x8 vrA[8], vrB[8], krA[4], krB[4];

    auto loadK = [&](int t, bf16x8 (&kr)[4]){
        const short* kp = kb + kbase + (size_t)(t*64 + nhalf*32 + c16)*64 + 8*g;
        kr[0] = *(const bf16x8*)kp;
        kr[1] = *(const bf16x8*)(kp + 32);
        kr[2] = *(const bf16x8*)(kp + 16*64);
        kr[3] = *(const bf16x8*)(kp + 16*64 + 32);
    };
    auto loadV = [&](int t, bf16x8 (&vr)[8]){
#pragma unroll
        for (int h = 0; h < 2; ++h)
#pragma unroll
            for (int cf = 0; cf < 4; ++cf)
                vr[h*4+cf] = *(const bf16x8*)(vb + ((size_t)b*NC + c0w + cf*16 + c16)*NPIX
                                              + t*64 + h*32 + 8*g);
    };

    auto compA = [&](bf16x8 kA, bf16x8 kB, int fn, char* pb){
        f32x4 s = (f32x4){0.f,0.f,0.f,0.f};
        s = __builtin_amdgcn_mfma_f32_16x16x32_bf16(kA, qa0, s, 0,0,0);
        s = __builtin_amdgcn_mfma_f32_16x16x32_bf16(kB, qa1, s, 0,0,0);
        u16x4 pk;
#pragma unroll
        for (int i = 0; i < 4; ++i){
            float p = exp2f(fmaf(s[i], LOG2E, -C0TERM));
            Lacc += p;
            pk[i] = (unsigned short)f2bf(p);
        }
        int nrel0 = nhalf*32 + fn*16 + 4*g;
        *(u16x4*)(pb + mrow*128 + ((2*nrel0) ^ swz)) = pk;
    };

    auto phaseB = [&](const char* pc, const bf16x8 (&vr)[8]){
#pragma unroll
        for (int h = 0; h < 2; ++h){
            bf16x8 pa[4];
#pragma unroll
            for (int f = 0; f < 4; ++f){
                int row = f*16 + c16;
                pa[f] = *(const bf16x8*)(pc + row*128 + ((h*64 + g*16) ^ ((row&7)<<4)));
            }
#pragma unroll
            for (int cf = 0; cf < 4; ++cf)
#pragma unroll
                for (int f = 0; f < 4; ++f)
                    acc[f][cf] = __builtin_amdgcn_mfma_f32_16x16x32_bf16(pa[f], vr[h*4+cf], acc[f][cf], 0,0,0);
        }
    };

    auto iter = [&](int t, char* bufA, const char* bufB,
                    const bf16x8 (&vcur)[8], bf16x8 (&vnext)[8],
                    const bf16x8 (&kcur)[4], bf16x8 (&knext)[4]){
        loadV(t+1, vnext);
        loadK(t+2 < 64 ? t+2 : 63, knext);
        __builtin_amdgcn_s_setprio(1);
        phaseB(bufB, vcur);
        __builtin_amdgcn_s_setprio(0);
        compA(kcur[0], kcur[1], 0, bufA);
        compA(kcur[2], kcur[3], 1, bufA);
        asm volatile("s_waitcnt lgkmcnt(0)" ::: "memory");
        __builtin_amdgcn_s_barrier();
    };

    loadV(0, vrA);
    loadK(0, krA);
    loadK(1, krB);
    compA(krA[0], krA[1], 0, Pb0);
    compA(krA[2], krA[3], 1, Pb0);
    asm volatile("s_waitcnt lgkmcnt(0)" ::: "memory");
    __builtin_amdgcn_s_barrier();

    for (int t2 = 0; t2 < 31; ++t2){
        iter(2*t2,     Pb1, Pb0, vrA, vrB, krB, krA);
        iter(2*t2 + 1, Pb0, Pb1, vrB, vrA, krA, krB);
    }
    iter(62, Pb1, Pb0, vrA, vrB, krB, krA);
    __builtin_amdgcn_s_setprio(1);
    phaseB(Pb1, vrB);
    __builtin_amdgcn_s_setprio(0);

    Lacc += __shfl_xor(Lacc, 16);
    Lacc += __shfl_xor(Lacc, 32);
    if (lane < 16) Lred[nhalf*64 + msubA + lane] = Lacc;
    __syncthreads();

    float gm = gamma[0];
#pragma unroll
    for (int f = 0; f < 4; ++f){
        float sc[4];
#pragma unroll
        for (int i = 0; i < 4; ++i){
            int r = f*16 + 4*g + i;
            float Ls = Lred[r] + Lred[64 + r];
            sc[i] = gm / Ls;
        }
#pragma unroll
        for (int cf = 0; cf < 4; ++cf){
            int c = c0w + cf*16 + c16;
            size_t base = ((size_t)b*NC + c)*NPIX + m0 + f*16 + 4*g;
            f32x4 v1 = *(const f32x4*)(view1 + base);
            f32x4 r;
#pragma unroll
            for (int i = 0; i < 4; ++i) r[i] = sc[i]*acc[f][cf][i] + v1[i];
            *(f32x4*)(out + base) = r;
        }
    }
}

extern "C" void kernel_launch(void* const* d_in, const int* in_sizes, int n_in,
                              void* d_out, int out_size, void* d_ws, size_t ws_size,
                              hipStream_t stream){
    const float* view1 = (const float*)d_in[0];
    const float* view2 = (const float*)d_in[1];
    const float* Wq    = (const float*)d_in[2];
    const float* bq    = (const float*)d_in[3];
    const float* Wk    = (const float*)d_in[4];
    const float* bk    = (const float*)d_in[5];
    const float* Wv    = (const float*)d_in[6];
    const float* bv    = (const float*)d_in[7];
    const float* gamma = (const float*)d_in[8];
    float* out = (float*)d_out;

    char* ws = (char*)d_ws;
    short* qbuf = (short*)(ws);                                   // 4 MB  (B,N,64) bf16
    short* kbuf = (short*)(ws + (size_t)4*1024*1024);             // 4 MB  (B,N,64) bf16
    short* vbuf = (short*)(ws + (size_t)8*1024*1024);             // 32 MB (B,C,N) bf16
    short* wqb  = (short*)(ws + (size_t)40*1024*1024);            // 64 KB
    short* wkb  = (short*)(ws + (size_t)40*1024*1024 + 64*1024);  // 64 KB
    short* wvb  = (short*)(ws + (size_t)40*1024*1024 + 128*1024); // 512 KB
    float* scl  = (float*)(ws + (size_t)41*1024*1024);            // 128 KB (chunk-local)
    float* Lpart= (float*)(ws + (size_t)42*1024*1024);            // 8 MB max (chunk-local)
    short* Pbuf = (short*)(ws + (size_t)50*1024*1024);            // 32 MB * nbc

    const size_t FIXED = (size_t)50*1024*1024;
    const size_t PPB   = (size_t)NPIX*NPIX*2;   // 32 MB per batch
    int avail = 0;
    if (ws_size > FIXED){
        size_t nn = (ws_size - FIXED) / PPB;
        avail = nn > 8 ? 8 : (int)nn;
    }
    // balanced chunks: {8} or {4,4} or {2,2,2,2} or {1..} — avoids low-occupancy tail
    int nbc = (avail >= 8) ? 8 : (avail >= 4) ? 4 : (avail >= 2) ? 2 : avail;

    hipLaunchKernelGGL(k_wconv, dim3(1024), dim3(256), 0, stream, Wq, Wk, Wv, wqb, wkb, wvb);
    hipLaunchKernelGGL(k_projq,  dim3(64, 8),  dim3(256), 0, stream, view1, wqb, bq, qbuf);
    hipLaunchKernelGGL(k_projkv, dim3(128, 8), dim3(256), 0, stream, view2, wvb, bv, wkb, bk, vbuf, kbuf);

    if (nbc >= 1){
        for (int b0 = 0; b0 < NB; b0 += nbc){
            int nb = (NB - b0 < nbc) ? (NB - b0) : nbc;
            hipLaunchKernelGGL(k_qk,   dim3(64, 16, nb), dim3(256), 0, stream, qbuf, kbuf, Pbuf, Lpart, b0);
            hipLaunchKernelGGL(k_lred, dim3(nb*16),      dim3(256), 0, stream, Lpart, gamma, scl);
            hipLaunchKernelGGL(k_pv,   dim3(4, 32, nb),  dim3(256), 0, stream, vbuf, Pbuf, scl, view1, out, b0);
        }
    } else {
        hipLaunchKernelGGL(k_attn, dim3(512), dim3(512), 0, stream, qbuf, kbuf, vbuf, view1, gamma, out);
    }
}

// Round 9
// 412.977 us; speedup vs baseline: 1.6461x; 1.1099x over previous
//
#include <hip/hip_runtime.h>

#define NB 8
#define NC 512
#define NPIX 4096
#define LOG2E 1.44269504088896340736f
#define C0TERM 28.853900817779268f   // 20*log2(e): p = exp2(s*log2e - C0TERM) = exp(s-20)

typedef __attribute__((ext_vector_type(4))) float f32x4;
typedef __attribute__((ext_vector_type(8))) short bf16x8;
typedef __attribute__((ext_vector_type(4))) unsigned short u16x4;

static __device__ __forceinline__ short f2bf(float f){
    union { float f; unsigned u; } v; v.f = f;
    unsigned r = v.u + 0x7fffu + ((v.u >> 16) & 1u);
    return (short)(r >> 16);
}

static __device__ __forceinline__ void gload16(const void* g, void* l){
    __builtin_amdgcn_global_load_lds(
        (const __attribute__((address_space(1))) char*)g,
        (__attribute__((address_space(3))) char*)l, 16, 0, 0);
}

// ---------------- weight f32 -> bf16 ----------------
__global__ void k_wconv(const float* __restrict__ wq, const float* __restrict__ wk,
                        const float* __restrict__ wv,
                        short* __restrict__ wqb, short* __restrict__ wkb,
                        short* __restrict__ wvb){
    int i = blockIdx.x * 256 + threadIdx.x;
    if (i < 64*NC){ wqb[i] = f2bf(wq[i]); wkb[i] = f2bf(wk[i]); }
    if (i < NC*NC){ wvb[i] = f2bf(wv[i]); }
}

// ---------------- Q projection (O=64) ----------------
__global__ __launch_bounds__(256) void k_projq(const float* __restrict__ X,
                                               const short* __restrict__ W,
                                               const float* __restrict__ bias,
                                               short* __restrict__ out){
    const int b = blockIdx.y;
    const int wv = threadIdx.x >> 6;
    const int lane = threadIdx.x & 63;
    const int g = lane >> 4, c16 = lane & 15;
    const int n0w = blockIdx.x * 64 + wv * 16;
    const float* Xb = X + (size_t)b * NC * NPIX;

    f32x4 acc[4];
#pragma unroll
    for (int f = 0; f < 4; ++f) acc[f] = (f32x4){0.f,0.f,0.f,0.f};

    for (int c0 = 0; c0 < NC; c0 += 32){
        bf16x8 a;
#pragma unroll
        for (int j = 0; j < 8; ++j)
            a[j] = f2bf(Xb[(size_t)(c0 + 8*g + j) * NPIX + n0w + c16]);
#pragma unroll
        for (int f = 0; f < 4; ++f){
            bf16x8 bfr = *(const bf16x8*)(W + (size_t)(f*16 + c16) * NC + c0 + 8*g);
            acc[f] = __builtin_amdgcn_mfma_f32_16x16x32_bf16(a, bfr, acc[f], 0, 0, 0);
        }
    }
#pragma unroll
    for (int f = 0; f < 4; ++f){
        int o = f*16 + c16;
        float bo = bias[o];
#pragma unroll
        for (int i = 0; i < 4; ++i)
            out[((size_t)b*NPIX + n0w + 4*g + i)*64 + o] = f2bf(acc[f][i] + bo);
    }
}

// ---------------- transpose+convert: X[b][c][n] f32 -> Xt[b][n][c] bf16 ----------------
// 64x64 tiles via LDS; coalesced read (float4) and write (16B/lane).
__global__ __launch_bounds__(256) void k_trans(const float* __restrict__ X,
                                               short* __restrict__ Xt){
    __shared__ __align__(16) short T[64][72];   // pad to 72 shorts (144B, 16B-mult)
    const int n0 = blockIdx.x * 64;
    const int c0 = blockIdx.y * 64;
    const int b  = blockIdx.z;
    const int t  = threadIdx.x;
    {
        const int cl = t >> 2;              // 0..63
        const int nq = (t & 3) * 16;        // 0,16,32,48
        const float* src = X + ((size_t)b*NC + c0 + cl)*NPIX + n0 + nq;
#pragma unroll
        for (int q = 0; q < 4; ++q){
            f32x4 v = *(const f32x4*)(src + q*4);
#pragma unroll
            for (int i = 0; i < 4; ++i)
                T[nq + q*4 + i][cl] = f2bf(v[i]);
        }
    }
    __syncthreads();
    {
        const int n  = t >> 2;
        const int cs = (t & 3) * 16;
        short* dst = Xt + ((size_t)b*NPIX + n0 + n)*NC + c0 + cs;
        *(f32x4*)dst       = *(const f32x4*)&T[n][cs];
        *(f32x4*)(dst + 8) = *(const f32x4*)&T[n][cs + 8];
    }
}

// ---------------- V projection as row-major GEMM ----------------
// V[o][n] = bv[o] + sum_c Wv[o][c] * Xt[n][c]; both operands K-contiguous 16B loads.
// 256 thr / 4 waves; tile 128o x 128n; wave (wo=wv&1, wn=wv>>1) -> 64o x 64n.
// acc[nf][of] = mfma(A=Xt-frag(rows=n), B=W-frag(rows=o)): n -> 4g+i, o -> c16.
__global__ __launch_bounds__(256) void k_projv(const short* __restrict__ Xt,
                                               const short* __restrict__ W,
                                               const float* __restrict__ bias,
                                               short* __restrict__ vout){
    const int o0 = blockIdx.x * 128;
    const int n0 = blockIdx.y * 128;
    const int b  = blockIdx.z;
    const int wv = threadIdx.x >> 6;
    const int lane = threadIdx.x & 63;
    const int g = lane >> 4, c16 = lane & 15;
    const int wo = wv & 1, wn = wv >> 1;

    const short* Xb = Xt + ((size_t)b*NPIX + n0 + wn*64)*NC;
    const short* Wb = W + (size_t)(o0 + wo*64)*NC;

    f32x4 acc[4][4];
#pragma unroll
    for (int nf = 0; nf < 4; ++nf)
#pragma unroll
        for (int of = 0; of < 4; ++of) acc[nf][of] = (f32x4){0.f,0.f,0.f,0.f};

    for (int c0 = 0; c0 < NC; c0 += 32){
        bf16x8 af[4], bf_[4];
#pragma unroll
        for (int f = 0; f < 4; ++f){
            af[f]  = *(const bf16x8*)(Xb + (size_t)(f*16 + c16)*NC + c0 + 8*g);
            bf_[f] = *(const bf16x8*)(Wb + (size_t)(f*16 + c16)*NC + c0 + 8*g);
        }
#pragma unroll
        for (int nf = 0; nf < 4; ++nf)
#pragma unroll
            for (int of = 0; of < 4; ++of)
                acc[nf][of] = __builtin_amdgcn_mfma_f32_16x16x32_bf16(af[nf], bf_[of], acc[nf][of], 0,0,0);
    }

#pragma unroll
    for (int of = 0; of < 4; ++of){
        int o = o0 + wo*64 + of*16 + c16;
        float bo = bias[o];
#pragma unroll
        for (int nf = 0; nf < 4; ++nf){
            int n = n0 + wn*64 + nf*16 + 4*g;
            u16x4 pk;
#pragma unroll
            for (int i = 0; i < 4; ++i) pk[i] = (unsigned short)f2bf(acc[nf][of][i] + bo);
            *(u16x4*)(vout + ((size_t)b*NC + o)*NPIX + n) = pk;
        }
    }
}

// ---------------- K projection as row-major GEMM ----------------
// K[n][o] = bk[o] + sum_c Wk[o][c] * Xt[n][c]
// 256 thr / 4 waves; tile 256n x 64o; wave wv -> n-sub 64.
// acc[of][nf] = mfma(A=Wk-frag(rows=o), B=Xt-frag(rows=n)): o -> 4g+i, n -> c16.
__global__ __launch_bounds__(256) void k_projk(const short* __restrict__ Xt,
                                               const short* __restrict__ W,
                                               const float* __restrict__ bias,
                                               short* __restrict__ kout){
    const int n0 = blockIdx.x * 256;
    const int b  = blockIdx.y;
    const int wv = threadIdx.x >> 6;
    const int lane = threadIdx.x & 63;
    const int g = lane >> 4, c16 = lane & 15;

    const short* Xb = Xt + ((size_t)b*NPIX + n0 + wv*64)*NC;

    f32x4 acc[4][4];
#pragma unroll
    for (int of = 0; of < 4; ++of)
#pragma unroll
        for (int nf = 0; nf < 4; ++nf) acc[of][nf] = (f32x4){0.f,0.f,0.f,0.f};

    for (int c0 = 0; c0 < NC; c0 += 32){
        bf16x8 af[4], bf_[4];
#pragma unroll
        for (int f = 0; f < 4; ++f){
            af[f]  = *(const bf16x8*)(W + (size_t)(f*16 + c16)*NC + c0 + 8*g);
            bf_[f] = *(const bf16x8*)(Xb + (size_t)(f*16 + c16)*NC + c0 + 8*g);
        }
#pragma unroll
        for (int of = 0; of < 4; ++of)
#pragma unroll
            for (int nf = 0; nf < 4; ++nf)
                acc[of][nf] = __builtin_amdgcn_mfma_f32_16x16x32_bf16(af[of], bf_[nf], acc[of][nf], 0,0,0);
    }

#pragma unroll
    for (int nf = 0; nf < 4; ++nf){
        int n = n0 + wv*64 + nf*16 + c16;
#pragma unroll
        for (int of = 0; of < 4; ++of){
            int o = of*16 + 4*g;
            u16x4 pk;
#pragma unroll
            for (int i = 0; i < 4; ++i) pk[i] = (unsigned short)f2bf(acc[of][nf][i] + bias[o+i]);
            *(u16x4*)(kout + ((size_t)b*NPIX + n)*64 + o) = pk;
        }
    }
}

// ---------------- old fused K+V projection (fallback path only) ----------------
__global__ __launch_bounds__(256) void k_projkv(const float* __restrict__ X,
                                                const short* __restrict__ Wv_,
                                                const float* __restrict__ bv_,
                                                const short* __restrict__ Wk_,
                                                const float* __restrict__ bk_,
                                                short* __restrict__ vout,
                                                short* __restrict__ kout){
    const int b = blockIdx.y;
    const int wv = threadIdx.x >> 6;
    const int lane = threadIdx.x & 63;
    const int g = lane >> 4, c16 = lane & 15;
    const int n0w = blockIdx.x * 32 + (wv & 1) * 16;
    const int oh = wv >> 1;
    const int o0v = oh * 256;
    const int o0k = oh * 32;
    const float* Xb = X + (size_t)b * NC * NPIX;

    f32x4 accv[16], acck[2];
#pragma unroll
    for (int f = 0; f < 16; ++f) accv[f] = (f32x4){0.f,0.f,0.f,0.f};
#pragma unroll
    for (int f = 0; f < 2;  ++f) acck[f] = (f32x4){0.f,0.f,0.f,0.f};

    for (int c0 = 0; c0 < NC; c0 += 32){
        bf16x8 a;
#pragma unroll
        for (int j = 0; j < 8; ++j)
            a[j] = f2bf(Xb[(size_t)(c0 + 8*g + j) * NPIX + n0w + c16]);
#pragma unroll
        for (int f = 0; f < 16; ++f){
            bf16x8 bfr = *(const bf16x8*)(Wv_ + (size_t)(o0v + f*16 + c16) * NC + c0 + 8*g);
            accv[f] = __builtin_amdgcn_mfma_f32_16x16x32_bf16(a, bfr, accv[f], 0, 0, 0);
        }
#pragma unroll
        for (int f = 0; f < 2; ++f){
            bf16x8 bfr = *(const bf16x8*)(Wk_ + (size_t)(o0k + f*16 + c16) * NC + c0 + 8*g);
            acck[f] = __builtin_amdgcn_mfma_f32_16x16x32_bf16(a, bfr, acck[f], 0, 0, 0);
        }
    }
#pragma unroll
    for (int f = 0; f < 16; ++f){
        int o = o0v + f*16 + c16;
        float bo = bv_[o];
        u16x4 pk;
#pragma unroll
        for (int i = 0; i < 4; ++i) pk[i] = (unsigned short)f2bf(accv[f][i] + bo);
        *(u16x4*)(vout + ((size_t)b*NC + o)*NPIX + n0w + 4*g) = pk;
    }
#pragma unroll
    for (int f = 0; f < 2; ++f){
        int o = o0k + f*16 + c16;
        float bo = bk_[o];
#pragma unroll
        for (int i = 0; i < 4; ++i)
            kout[((size_t)b*NPIX + n0w + 4*g + i)*64 + o] = f2bf(acck[f][i] + bo);
    }
}

// ---------------- pass 1: P = exp(QK^T - 20) bf16 (coalesced via LDS), L partials ----
__global__ __launch_bounds__(256) void k_qk(const short* __restrict__ qb,
                                            const short* __restrict__ kb,
                                            short* __restrict__ P,
                                            float* __restrict__ Lpart,
                                            int b0){
    __shared__ __align__(16) short Pt[64*256];     // 32 KB, row stride 512B
    const int m0 = blockIdx.x * 64;
    const int n0 = blockIdx.y * 256;
    const int bz = blockIdx.z;
    const int b  = b0 + bz;
    const int wv = threadIdx.x >> 6;
    const int lane = threadIdx.x & 63;
    const int g = lane >> 4, c16 = lane & 15;
    const int nsub = wv * 64;

    bf16x8 qf[4][2];
#pragma unroll
    for (int mf = 0; mf < 4; ++mf)
#pragma unroll
        for (int kk = 0; kk < 2; ++kk)
            qf[mf][kk] = *(const bf16x8*)(qb + ((size_t)b*NPIX + m0 + mf*16 + c16)*64 + kk*32 + 8*g);

    float lsum[4] = {0.f,0.f,0.f,0.f};
    char* Ptb = (char*)Pt;

#pragma unroll
    for (int nf = 0; nf < 4; ++nf){
        bf16x8 kf0 = *(const bf16x8*)(kb + ((size_t)b*NPIX + n0 + nsub + nf*16 + c16)*64 + 8*g);
        bf16x8 kf1 = *(const bf16x8*)(kb + ((size_t)b*NPIX + n0 + nsub + nf*16 + c16)*64 + 32 + 8*g);
#pragma unroll
        for (int mf = 0; mf < 4; ++mf){
            f32x4 s = (f32x4){0.f,0.f,0.f,0.f};
            s = __builtin_amdgcn_mfma_f32_16x16x32_bf16(kf0, qf[mf][0], s, 0,0,0);
            s = __builtin_amdgcn_mfma_f32_16x16x32_bf16(kf1, qf[mf][1], s, 0,0,0);
            u16x4 pk;
#pragma unroll
            for (int i = 0; i < 4; ++i){
                float p = exp2f(fmaf(s[i], LOG2E, -C0TERM));
                lsum[mf] += p;
                pk[i] = (unsigned short)f2bf(p);
            }
            int m = mf*16 + c16;
            int ncol = nsub + nf*16 + 4*g;
            *(u16x4*)(Ptb + m*512 + ((2*ncol) ^ ((m&7)<<4))) = pk;
        }
    }
    __syncthreads();

    {
        char* Pgb = (char*)(P + ((size_t)bz*NPIX + m0)*NPIX + n0);
        const int chunk = threadIdx.x & 31;
        const int row8  = threadIdx.x >> 5;
#pragma unroll
        for (int p = 0; p < 8; ++p){
            int row = p*8 + row8;
            f32x4 v = *(const f32x4*)(Ptb + row*512 + ((chunk*16) ^ ((row&7)<<4)));
            *(f32x4*)(Pgb + (size_t)row*(NPIX*2) + chunk*16) = v;
        }
    }

#pragma unroll
    for (int mf = 0; mf < 4; ++mf){
        lsum[mf] += __shfl_xor(lsum[mf], 16);
        lsum[mf] += __shfl_xor(lsum[mf], 32);
    }
    if (lane < 16){
        size_t base = ((size_t)bz*64 + blockIdx.y*4 + wv)*NPIX + m0 + lane;
#pragma unroll
        for (int mf = 0; mf < 4; ++mf)
            Lpart[base + mf*16] = lsum[mf];
    }
}

// ---------------- L reduce: scale[bz][m] = gamma / sum ----------------
__global__ __launch_bounds__(256) void k_lred(const float* __restrict__ Lpart,
                                              const float* __restrict__ gamma,
                                              float* __restrict__ scale){
    int idx = blockIdx.x * 256 + threadIdx.x;
    int bz = idx >> 12, m = idx & 4095;
    float s = 0.f;
    for (int sl = 0; sl < 64; ++sl)
        s += Lpart[((size_t)bz*64 + sl)*NPIX + m];
    scale[idx] = gamma[0] / s;
}

// ---------------- pass 2: PV GEMM (m97 + T2 swizzle) + epilogue ----------------
__global__ __launch_bounds__(256) void k_pv(const short* __restrict__ vb,
                                            const short* __restrict__ P,
                                            const float* __restrict__ scale,
                                            const float* __restrict__ view1,
                                            float* __restrict__ out,
                                            int b0){
    __shared__ __align__(16) short At[2][128*64];
    __shared__ __align__(16) short Bt[2][128*64];
    const int p  = blockIdx.x + 4*blockIdx.y;
    const int mt = (p & 7) | (((p >> 5) & 3) << 3);
    const int ct = (p >> 3) & 3;
    const int c0 = ct * 128;
    const int m0 = mt * 128;
    const int bz = blockIdx.z;
    const int b  = b0 + bz;
    const int wv = threadIdx.x >> 6;
    const int lane = threadIdx.x & 63;
    const int g = lane >> 4, c16 = lane & 15;
    const int wc = wv & 1, wm = wv >> 1;
    const int lrow = lane >> 3;
    const int srcg = (lane & 7) ^ lrow;
    const int swz  = (c16 & 7) << 4;

    const char* Vg = (const char*)(vb + ((size_t)b*NC + c0)*NPIX);
    const char* Pg = (const char*)(P + ((size_t)bz*NPIX + m0)*NPIX);

    f32x4 acc[4][4];
#pragma unroll
    for (int cf = 0; cf < 4; ++cf)
#pragma unroll
        for (int mf = 0; mf < 4; ++mf) acc[cf][mf] = (f32x4){0.f,0.f,0.f,0.f};

    auto stage = [&](int buf, int t){
        size_t nbyte = (size_t)t * 64 * 2;
#pragma unroll
        for (int j = 0; j < 4; ++j){
            int r0 = wv*32 + j*8;
            int row = r0 + lrow;
            gload16(Vg + (size_t)row*(NPIX*2) + nbyte + srcg*16, (char*)&At[buf][0] + r0*128);
            gload16(Pg + (size_t)row*(NPIX*2) + nbyte + srcg*16, (char*)&Bt[buf][0] + r0*128);
        }
    };

    stage(0, 0);
    __syncthreads();

    for (int t = 0; t < 64; ++t){
        int buf = t & 1;
        if (t < 63) stage(buf ^ 1, t + 1);
        const char* A  = (const char*)&At[buf][0];
        const char* Bp = (const char*)&Bt[buf][0];
#pragma unroll
        for (int kk = 0; kk < 2; ++kk){
            bf16x8 af[4], bfm[4];
#pragma unroll
            for (int f = 0; f < 4; ++f){
                af[f]  = *(const bf16x8*)(A  + (wc*64 + f*16 + c16)*128 + ((kk*64 + g*16) ^ swz));
                bfm[f] = *(const bf16x8*)(Bp + (wm*64 + f*16 + c16)*128 + ((kk*64 + g*16) ^ swz));
            }
#pragma unroll
            for (int cf = 0; cf < 4; ++cf)
#pragma unroll
                for (int mf = 0; mf < 4; ++mf)
                    acc[cf][mf] = __builtin_amdgcn_mfma_f32_16x16x32_bf16(af[cf], bfm[mf], acc[cf][mf], 0,0,0);
        }
        __syncthreads();
    }

    float sc[4];
#pragma unroll
    for (int mf = 0; mf < 4; ++mf)
        sc[mf] = scale[(size_t)bz*NPIX + m0 + wm*64 + mf*16 + c16];
#pragma unroll
    for (int cf = 0; cf < 4; ++cf){
#pragma unroll
        for (int mf = 0; mf < 4; ++mf){
            int m = m0 + wm*64 + mf*16 + c16;
#pragma unroll
            for (int i = 0; i < 4; ++i){
                int c = c0 + wc*64 + cf*16 + 4*g + i;
                size_t idx = ((size_t)b*NC + c)*NPIX + m;
                out[idx] = sc[mf]*acc[cf][mf][i] + view1[idx];
            }
        }
    }
}

// ================= fallback fused attention (R4, 390us) — used if ws too small =========
__global__ __launch_bounds__(512, 2) void k_attn(const short* __restrict__ qb,
                                                 const short* __restrict__ kb,
                                                 const short* __restrict__ vb,
                                                 const float* __restrict__ view1,
                                                 const float* __restrict__ gamma,
                                                 float* __restrict__ out){
    __shared__ __align__(16) short P[2][64*64];
    __shared__ float Lred[128];

    const int bid = blockIdx.x;
    const int b  = bid & 7;
    const int m0 = (bid >> 3) * 64;
    const int wv = threadIdx.x >> 6;
    const int lane = threadIdx.x & 63;
    const int g = lane >> 4, c16 = lane & 15;
    const int msubA = (wv & 3) * 16;
    const int nhalf = wv >> 2;
    const int c0w = wv * 64;

    const short* qrow = qb + ((size_t)b*NPIX + m0 + msubA + c16)*64 + 8*g;
    bf16x8 qa0 = *(const bf16x8*)qrow;
    bf16x8 qa1 = *(const bf16x8*)(qrow + 32);

    const size_t kbase = (size_t)b * NPIX * 64;
    const int mrow = msubA + c16;
    const int swz = (mrow & 7) << 4;
    float Lacc = 0.f;

    f32x4 acc[4][4];
#pragma unroll
    for (int f = 0; f < 4; ++f)
#pragma unroll
        for (int cf = 0; cf < 4; ++cf) acc[f][cf] = (f32x4){0.f,0.f,0.f,0.f};

    char* Pb0 = (char*)&P[0][0];
    char* Pb1 = (char*)&P[1][0];

    bf16x8 vrA[8], vrB[8], krA[4], krB[4];

    auto loadK = [&](int t, bf16x8 (&kr)[4]){
        const short* kp = kb + kbase + (size_t)(t*64 + nhalf*32 + c16)*64 + 8*g;
        kr[0] = *(const bf16x8*)kp;
        kr[1] = *(const bf16x8*)(kp + 32);
        kr[2] = *(const bf16x8*)(kp + 16*64);
        kr[3] = *(const bf16x8*)(kp + 16*64 + 32);
    };
    auto loadV = [&](int t, bf16x8 (&vr)[8]){
#pragma unroll
        for (int h = 0; h < 2; ++h)
#pragma unroll
            for (int cf = 0; cf < 4; ++cf)
                vr[h*4+cf] = *(const bf16x8*)(vb + ((size_t)b*NC + c0w + cf*16 + c16)*NPIX
                                              + t*64 + h*32 + 8*g);
    };

    auto compA = [&](bf16x8 kA, bf16x8 kB, int fn, char* pb){
        f32x4 s = (f32x4){0.f,0.f,0.f,0.f};
        s = __builtin_amdgcn_mfma_f32_16x16x32_bf16(kA, qa0, s, 0,0,0);
        s = __builtin_amdgcn_mfma_f32_16x16x32_bf16(kB, qa1, s, 0,0,0);
        u16x4 pk;
#pragma unroll
        for (int i = 0; i < 4; ++i){
            float p = exp2f(fmaf(s[i], LOG2E, -C0TERM));
            Lacc += p;
            pk[i] = (unsigned short)f2bf(p);
        }
        int nrel0 = nhalf*32 + fn*16 + 4*g;
        *(u16x4*)(pb + mrow*128 + ((2*nrel0) ^ swz)) = pk;
    };

    auto phaseB = [&](const char* pc, const bf16x8 (&vr)[8]){
#pragma unroll
        for (int h = 0; h < 2; ++h){
            bf16x8 pa[4];
#pragma unroll
            for (int f = 0; f < 4; ++f){
                int row = f*16 + c16;
                pa[f] = *(const bf16x8*)(pc + row*128 + ((h*64 + g*16) ^ ((row&7)<<4)));
            }
#pragma unroll
            for (int cf = 0; cf < 4; ++cf)
#pragma unroll
                for (int f = 0; f < 4; ++f)
                    acc[f][cf] = __builtin_amdgcn_mfma_f32_16x16x32_bf16(pa[f], vr[h*4+cf], acc[f][cf], 0,0,0);
        }
    };

    auto iter = [&](int t, char* bufA, const char* bufB,
                    const bf16x8 (&vcur)[8], bf16x8 (&vnext)[8],
                    const bf16x8 (&kcur)[4], bf16x8 (&knext)[4]){
        loadV(t+1, vnext);
        loadK(t+2 < 64 ? t+2 : 63, knext);
        __builtin_amdgcn_s_setprio(1);
        phaseB(bufB, vcur);
        __builtin_amdgcn_s_setprio(0);
        compA(kcur[0], kcur[1], 0, bufA);
        compA(kcur[2], kcur[3], 1, bufA);
        asm volatile("s_waitcnt lgkmcnt(0)" ::: "memory");
        __builtin_amdgcn_s_barrier();
    };

    loadV(0, vrA);
    loadK(0, krA);
    loadK(1, krB);
    compA(krA[0], krA[1], 0, Pb0);
    compA(krA[2], krA[3], 1, Pb0);
    asm volatile("s_waitcnt lgkmcnt(0)" ::: "memory");
    __builtin_amdgcn_s_barrier();

    for (int t2 = 0; t2 < 31; ++t2){
        iter(2*t2,     Pb1, Pb0, vrA, vrB, krB, krA);
        iter(2*t2 + 1, Pb0, Pb1, vrB, vrA, krA, krB);
    }
    iter(62, Pb1, Pb0, vrA, vrB, krB, krA);
    __builtin_amdgcn_s_setprio(1);
    phaseB(Pb1, vrB);
    __builtin_amdgcn_s_setprio(0);

    Lacc += __shfl_xor(Lacc, 16);
    Lacc += __shfl_xor(Lacc, 32);
    if (lane < 16) Lred[nhalf*64 + msubA + lane] = Lacc;
    __syncthreads();

    float gm = gamma[0];
#pragma unroll
    for (int f = 0; f < 4; ++f){
        float sc[4];
#pragma unroll
        for (int i = 0; i < 4; ++i){
            int r = f*16 + 4*g + i;
            float Ls = Lred[r] + Lred[64 + r];
            sc[i] = gm / Ls;
        }
#pragma unroll
        for (int cf = 0; cf < 4; ++cf){
            int c = c0w + cf*16 + c16;
            size_t base = ((size_t)b*NC + c)*NPIX + m0 + f*16 + 4*g;
            f32x4 v1 = *(const f32x4*)(view1 + base);
            f32x4 r;
#pragma unroll
            for (int i = 0; i < 4; ++i) r[i] = sc[i]*acc[f][cf][i] + v1[i];
            *(f32x4*)(out + base) = r;
        }
    }
}

extern "C" void kernel_launch(void* const* d_in, const int* in_sizes, int n_in,
                              void* d_out, int out_size, void* d_ws, size_t ws_size,
                              hipStream_t stream){
    const float* view1 = (const float*)d_in[0];
    const float* view2 = (const float*)d_in[1];
    const float* Wq    = (const float*)d_in[2];
    const float* bq    = (const float*)d_in[3];
    const float* Wk    = (const float*)d_in[4];
    const float* bk    = (const float*)d_in[5];
    const float* Wv    = (const float*)d_in[6];
    const float* bv    = (const float*)d_in[7];
    const float* gamma = (const float*)d_in[8];
    float* out = (float*)d_out;

    char* ws = (char*)d_ws;
    short* qbuf = (short*)(ws);                                   // 4 MB  (B,N,64) bf16
    short* kbuf = (short*)(ws + (size_t)4*1024*1024);             // 4 MB  (B,N,64) bf16
    short* vbuf = (short*)(ws + (size_t)8*1024*1024);             // 32 MB (B,C,N) bf16
    short* wqb  = (short*)(ws + (size_t)40*1024*1024);            // 64 KB
    short* wkb  = (short*)(ws + (size_t)40*1024*1024 + 64*1024);  // 64 KB
    short* wvb  = (short*)(ws + (size_t)40*1024*1024 + 128*1024); // 512 KB
    float* scl  = (float*)(ws + (size_t)41*1024*1024);            // 128 KB (chunk-local)
    float* Lpart= (float*)(ws + (size_t)42*1024*1024);            // 8 MB max (chunk-local)
    short* Pbuf = (short*)(ws + (size_t)50*1024*1024);            // 32 MB * nbc
    short* X2t  = Pbuf;  // X2t (32 MB) aliases Pbuf[0:32MB]: used only BEFORE k_qk writes P

    const size_t FIXED = (size_t)50*1024*1024;
    const size_t PPB   = (size_t)NPIX*NPIX*2;   // 32 MB per batch
    int avail = 0;
    if (ws_size > FIXED){
        size_t nn = (ws_size - FIXED) / PPB;
        avail = nn > 8 ? 8 : (int)nn;
    }
    int nbc = (avail >= 8) ? 8 : (avail >= 4) ? 4 : (avail >= 2) ? 2 : avail;

    hipLaunchKernelGGL(k_wconv, dim3(1024), dim3(256), 0, stream, Wq, Wk, Wv, wqb, wkb, wvb);
    hipLaunchKernelGGL(k_projq,  dim3(64, 8),  dim3(256), 0, stream, view1, wqb, bq, qbuf);

    if (nbc >= 1){
        // fast projections via transposed view2 (X2t aliases Pbuf region, ws>=82MB proven)
        hipLaunchKernelGGL(k_trans, dim3(64, 8, 8), dim3(256), 0, stream, view2, X2t);
        hipLaunchKernelGGL(k_projv, dim3(4, 32, 8), dim3(256), 0, stream, X2t, wvb, bv, vbuf);
        hipLaunchKernelGGL(k_projk, dim3(16, 8),    dim3(256), 0, stream, X2t, wkb, bk, kbuf);
        for (int b0 = 0; b0 < NB; b0 += nbc){
            int nb = (NB - b0 < nbc) ? (NB - b0) : nbc;
            hipLaunchKernelGGL(k_qk,   dim3(64, 16, nb), dim3(256), 0, stream, qbuf, kbuf, Pbuf, Lpart, b0);
            hipLaunchKernelGGL(k_lred, dim3(nb*16),      dim3(256), 0, stream, Lpart, gamma, scl);
            hipLaunchKernelGGL(k_pv,   dim3(4, 32, nb),  dim3(256), 0, stream, vbuf, Pbuf, scl, view1, out, b0);
        }
    } else {
        hipLaunchKernelGGL(k_projkv, dim3(128, 8), dim3(256), 0, stream, view2, wvb, bv, wkb, bk, vbuf, kbuf);
        hipLaunchKernelGGL(k_attn, dim3(512), dim3(512), 0, stream, qbuf, kbuf, vbuf, view1, gamma, out);
    }
}